// Round 11
// baseline (155.613 us; speedup 1.0000x reference)
//
#include <hip/hip_runtime.h>
#include <math.h>

#define B 16
#define N 32
#define M 64
#define D 512
#define NM (N * M)          // 2048
#define NBQ (B * NM)        // 32768
#define NUM_NEGS 32
#define SMOOTHING 0.1f
#define TD0 (1.0f - SMOOTHING)                    // 0.9
#define TDN (SMOOTHING / (float)(NUM_NEGS - 1))   // 0.1/31
#define TDSUM (TD0 + (float)NUM_NEGS * TDN)

typedef __fp16 half2v __attribute__((ext_vector_type(2)));

__device__ __forceinline__ unsigned int pkh(float lo, float hi) {
    half2v h = __builtin_amdgcn_cvt_pkrtz(lo, hi);
    return __builtin_bit_cast(unsigned int, h);
}

__device__ __forceinline__ float fdot2_acc(unsigned int a, unsigned int b, float acc) {
#if __has_builtin(__builtin_amdgcn_fdot2)
    return __builtin_amdgcn_fdot2(__builtin_bit_cast(half2v, a),
                                  __builtin_bit_cast(half2v, b), acc, false);
#else
    half2v ha = __builtin_bit_cast(half2v, a);
    half2v hb = __builtin_bit_cast(half2v, b);
    return acc + (float)ha.x * (float)hb.x + (float)ha.y * (float)hb.y;
#endif
}

__device__ __forceinline__ float dot8h(uint4 a, uint4 b) {
    float acc = fdot2_acc(a.x, b.x, 0.0f);
    acc = fdot2_acc(a.y, b.y, acc);
    acc = fdot2_acc(a.z, b.z, acc);
    acc = fdot2_acc(a.w, b.w, acc);
    return acc;
}

// Streaming c -> f16 (16,777,216 floats, 8 per thread, 8192 x 256 exact).
__global__ __launch_bounds__(256) void convert_c_kernel(
    const float* __restrict__ c, uint4* __restrict__ cb)
{
    const size_t i = (size_t)blockIdx.x * 256 + threadIdx.x;
    const float4* cp = reinterpret_cast<const float4*>(c);
    const float4 a = cp[2 * i];
    const float4 b4 = cp[2 * i + 1];
    uint4 w;
    w.x = pkh(a.x, a.y);   w.y = pkh(a.z, a.w);
    w.z = pkh(b4.x, b4.y); w.w = pkh(b4.z, b4.w);
    cb[i] = w;
}

// ---------- main kernel: block-per-q, 4 independent waves, 1 barrier ----------
__global__ __launch_bounds__(256) void ce_main_f16_kernel(
    const float* __restrict__ s,              // (B, NM, D) fp32
    const uint4* __restrict__ cb,             // (B*NM, D/8) f16-packed rows
    const int* __restrict__ pad,
    const int* __restrict__ valid,
    const int* __restrict__ inds,
    float4* __restrict__ partials)
{
    __shared__ float dots[NUM_NEGS + 1];
    __shared__ int   colsh[NUM_NEGS + 1];
    __shared__ int   rowsh[NUM_NEGS + 1];

    // XCD-batch affinity swizzle: XCD x owns batches {x, x+8}.
    const int p  = blockIdx.x;
    const int x  = p & 7;
    const int i  = p >> 3;
    const int b  = x + ((i >> 11) << 3);
    const int q  = i & (NM - 1);
    const int bq = b * NM + q;

    const int tid  = threadIdx.x;
    const int wave = tid >> 6;
    const int lane = tid & 63;

    // Issue address-independent loads at entry: own s-row + pad.
    const float4* sp = reinterpret_cast<const float4*>(s + (size_t)bq * D);
    const float4 sa0 = sp[2 * lane];
    const float4 sa1 = sp[2 * lane + 1];
    int padraw = 0;
    if (tid == 0) padraw = pad[(size_t)bq * M];

    // Per-wave setup (no cross-wave deps, no barrier): wave w owns
    // j = w + 4k, k=0..7; wave 0 additionally owns j=32.
    // Wave-uniform inds loads broadcast across lanes; gathers issued as
    // addresses arrive.
    uint4 w32g = make_uint4(0, 0, 0, 0);
    if (wave == 0) {   // j = 32: issue earliest (wave 0 has 1 extra dot)
        const int base = (bq * NUM_NEGS + 31) * 3;
        const int bb = inds[base], rr = inds[base + 1], cc = inds[base + 2];
        const int col = bb * NM + cc, row = bb * NM + rr;
        if (lane == 0) { colsh[32] = col; rowsh[32] = row; }
        w32g = cb[(size_t)col * (D / 8) + lane];
        (void)row;
    }

    uint4 wg[8];
    #pragma unroll
    for (int k = 0; k < 8; ++k) {
        const int j = wave + 4 * k;
        int col, row;
        if (j == 0) {          // diagonal (wave 0, k = 0)
            col = bq; row = bq;
        } else {
            const int base = (bq * NUM_NEGS + (j - 1)) * 3;
            const int bb = inds[base], rr = inds[base + 1], cc = inds[base + 2];
            col = bb * NM + cc; row = bb * NM + rr;
        }
        if (lane == 0) { colsh[j] = col; rowsh[j] = row; }
        wg[k] = cb[(size_t)col * (D / 8) + lane];
    }

    // Off-critical-path valid gather: lane L (<8, or ==8 on wave 0) loads the
    // vbit for j = wave + 4L, consumed only at the dots-write below.
    // valid idx = (bb*NM+rr)*NM + cc = row*2048 + (col & 2047).
    int vbit = 1;
    if (lane < 8 || (wave == 0 && lane == 8)) {
        const int j = wave + 4 * lane;
        if (j > 0) {
            const int col = colsh[j];   // same-wave LDS RAW (lane-0 wrote it)
            const int row = rowsh[j];
            vbit = valid[(size_t)row * NM + (col & (NM - 1))];
        }
    }

    // Own s-row fragment -> f16 registers (loads issued at entry).
    uint4 sh;
    sh.x = pkh(sa0.x, sa0.y); sh.y = pkh(sa0.z, sa0.w);
    sh.z = pkh(sa1.x, sa1.y); sh.w = pkh(sa1.z, sa1.w);

    float u[8];
    #pragma unroll
    for (int k = 0; k < 8; ++k) u[k] = dot8h(wg[k], sh);

    // Fold-reduce 8 values across 64 lanes: 3 folds + 3 butterflies.
    const int b0 = lane & 1, b1 = lane & 2, b2 = lane & 4;
    float n0 = (b0 ? u[1] : u[0]) + __shfl_xor(b0 ? u[0] : u[1], 1, 64);
    float n1 = (b0 ? u[3] : u[2]) + __shfl_xor(b0 ? u[2] : u[3], 1, 64);
    float n2 = (b0 ? u[5] : u[4]) + __shfl_xor(b0 ? u[4] : u[5], 1, 64);
    float n3 = (b0 ? u[7] : u[6]) + __shfl_xor(b0 ? u[6] : u[7], 1, 64);
    float m0 = (b1 ? n1 : n0) + __shfl_xor(b1 ? n0 : n1, 2, 64);
    float m1 = (b1 ? n3 : n2) + __shfl_xor(b1 ? n2 : n3, 2, 64);
    float w8 = (b2 ? m1 : m0) + __shfl_xor(b2 ? m0 : m1, 4, 64);
    w8 += __shfl_xor(w8, 8, 64);
    w8 += __shfl_xor(w8, 16, 64);
    w8 += __shfl_xor(w8, 32, 64);
    // Lane L holds dot (wave + 4L); lanes 0..7 write.
    if (lane < 8) {
        const int j = wave + 4 * lane;
        dots[j] = vbit ? w8 : 0.0f;
    }

    if (wave == 0) {   // dot 32 (gather issued at entry)
        float uu = dot8h(w32g, sh);
        #pragma unroll
        for (int off = 32; off; off >>= 1) uu += __shfl_xor(uu, off, 64);
        const int vb32 = __shfl(vbit, 8, 64);
        if (lane == 0) dots[32] = vb32 ? uu : 0.0f;
    }
    __syncthreads();

    // Wave-parallel epilogue on wave 0.
    if (wave == 0) {
        const float dj = (lane <= NUM_NEGS) ? dots[lane] : -INFINITY;
        float mx = dj;
        #pragma unroll
        for (int off = 32; off; off >>= 1) mx = fmaxf(mx, __shfl_xor(mx, off, 64));
        float e  = (lane <= NUM_NEGS) ? expf(dj - mx) : 0.0f;
        float sn = (lane >= 1 && lane <= NUM_NEGS) ? dj : 0.0f;
        #pragma unroll
        for (int off = 32; off; off >>= 1) {
            e  += __shfl_xor(e, off, 64);
            sn += __shfl_xor(sn, off, 64);
        }
        if (lane == 0) {
            const float num   = dj;             // dots[0]
            const float lse   = mx + logf(e);
            const float chunk = lse * TDSUM - (TD0 * num + TDN * sn);
            const float v     = padraw ? 0.0f : 1.0f;
            const float sim   = 1.0f - fminf(fmaxf(num, -1.0f), 1.0f);
            partials[bq] = make_float4(chunk * v, sim * v, v, 0.0f);
        }
    }
}

// ---------- fallback: fp32 gather (used only if ws too small) ----------
__global__ __launch_bounds__(256) void ce_main_fp32_kernel(
    const float* __restrict__ s, const float* __restrict__ c,
    const int* __restrict__ pad, const int* __restrict__ valid,
    const int* __restrict__ inds, float4* __restrict__ partials)
{
    __shared__ float dots[NUM_NEGS + 1];
    __shared__ int   colsh[NUM_NEGS + 1];
    __shared__ int   rowsh[NUM_NEGS + 1];
    __shared__ unsigned char vmsk[NUM_NEGS + 1];

    const int p  = blockIdx.x;
    const int x  = p & 7;
    const int i  = p >> 3;
    const int b  = x + ((i >> 11) << 3);
    const int q  = i & (NM - 1);
    const int bq = b * NM + q;

    const int tid  = threadIdx.x;
    const int wave = tid >> 6;
    const int lane = tid & 63;

    if (tid < NUM_NEGS + 1) {
        int col, srow, vb;
        if (tid == 0) { col = bq; srow = bq; vb = 1; }
        else {
            size_t si = ((size_t)bq * NUM_NEGS + (tid - 1)) * 3;
            int bb = inds[si + 0]; int rr = inds[si + 1]; int cc = inds[si + 2];
            col = bb * NM + cc; srow = bb * NM + rr;
            vb  = valid[((size_t)bb * NM + rr) * NM + cc] ? 1 : 0;
        }
        colsh[tid] = col; rowsh[tid] = srow; vmsk[tid] = (unsigned char)vb;
    }
    __syncthreads();

    const float4* sp = reinterpret_cast<const float4*>(s + (size_t)bq * D);
    const float4 s0 = sp[lane];
    const float4 s1 = sp[lane + 64];

    for (int j = wave; j < NUM_NEGS + 1; j += 4) {
        const float4* cp = reinterpret_cast<const float4*>(c + (size_t)colsh[j] * D);
        float4 c0 = cp[lane];
        float4 c1 = cp[lane + 64];
        float4 t0 = s0, t1 = s1;
        if (rowsh[j] != bq) {
            const float4* spx = reinterpret_cast<const float4*>(s + (size_t)rowsh[j] * D);
            t0 = spx[lane]; t1 = spx[lane + 64];
        }
        float sum = c0.x * t0.x + c0.y * t0.y + c0.z * t0.z + c0.w * t0.w
                  + c1.x * t1.x + c1.y * t1.y + c1.z * t1.z + c1.w * t1.w;
        #pragma unroll
        for (int off = 32; off; off >>= 1) sum += __shfl_down(sum, off, 64);
        if (lane == 0) dots[j] = vmsk[j] ? sum : 0.0f;
    }
    __syncthreads();

    if (wave == 0) {
        const float dj = (lane <= NUM_NEGS) ? dots[lane] : -INFINITY;
        float mx = dj;
        #pragma unroll
        for (int off = 32; off; off >>= 1) mx = fmaxf(mx, __shfl_xor(mx, off, 64));
        float e  = (lane <= NUM_NEGS) ? expf(dj - mx) : 0.0f;
        float sn = (lane >= 1 && lane <= NUM_NEGS) ? dj : 0.0f;
        #pragma unroll
        for (int off = 32; off; off >>= 1) { e += __shfl_xor(e, off, 64); sn += __shfl_xor(sn, off, 64); }
        if (lane == 0) {
            const float num   = dj;
            const float lse   = mx + logf(e);
            const float chunk = lse * TDSUM - (TD0 * num + TDN * sn);
            const float v     = pad[(size_t)bq * M] ? 0.0f : 1.0f;
            const float sim   = 1.0f - fminf(fmaxf(num, -1.0f), 1.0f);
            partials[bq] = make_float4(chunk * v, sim * v, v, 0.0f);
        }
    }
}

// Stage 2: 64 blocks x 256 threads, grid-stride over NBQ, one partial per block.
__global__ __launch_bounds__(256) void reduce_kernel(
    const float4* __restrict__ partials, float4* __restrict__ blk)
{
    __shared__ float red[3][4];
    float a = 0.0f, bsum = 0.0f, cnt = 0.0f;
    for (int i = blockIdx.x * 256 + threadIdx.x; i < NBQ; i += 64 * 256) {
        float4 pr = partials[i];
        a += pr.x; bsum += pr.y; cnt += pr.z;
    }
    #pragma unroll
    for (int off = 32; off; off >>= 1) {
        a    += __shfl_down(a, off, 64);
        bsum += __shfl_down(bsum, off, 64);
        cnt  += __shfl_down(cnt, off, 64);
    }
    const int wave = threadIdx.x >> 6;
    const int lane = threadIdx.x & 63;
    if (lane == 0) { red[0][wave] = a; red[1][wave] = bsum; red[2][wave] = cnt; }
    __syncthreads();
    if (threadIdx.x == 0) {
        blk[blockIdx.x] = make_float4(red[0][0] + red[0][1] + red[0][2] + red[0][3],
                                      red[1][0] + red[1][1] + red[1][2] + red[1][3],
                                      red[2][0] + red[2][1] + red[2][2] + red[2][3],
                                      0.0f);
    }
}

__global__ void finalize_kernel(const float4* __restrict__ blk,
                                float* __restrict__ out) {
    const int lane = threadIdx.x & 63;
    float4 pr = blk[lane];
    float a = pr.x, bsum = pr.y, cnt = pr.z;
    #pragma unroll
    for (int off = 32; off; off >>= 1) {
        a    += __shfl_down(a, off, 64);
        bsum += __shfl_down(bsum, off, 64);
        cnt  += __shfl_down(cnt, off, 64);
    }
    if (lane == 0) {
        out[0] = a / cnt;     // ce_loss
        out[1] = bsum / cnt;  // sim_loss
    }
}

extern "C" void kernel_launch(void* const* d_in, const int* in_sizes, int n_in,
                              void* d_out, int out_size, void* d_ws, size_t ws_size,
                              hipStream_t stream) {
    const float* s_ptr   = (const float*)d_in[0];
    const float* c_ptr   = (const float*)d_in[1];
    const int*   pad_ptr = (const int*)d_in[2];
    const int*   val_ptr = (const int*)d_in[3];
    const int*   ind_ptr = (const int*)d_in[4];
    float*       out_ptr = (float*)d_out;

    // ws layout: [0, 512K) partials; [512K, +1K) blk; [1M, 1M+32M) c_f16
    float4* partials = (float4*)d_ws;
    float4* blk      = (float4*)((char*)d_ws + (size_t)NBQ * sizeof(float4));
    uint4*  cb       = (uint4*)((char*)d_ws + (1u << 20));
    const size_t need = (1u << 20) + (size_t)B * NM * D * 2;

    if (ws_size >= need) {
        convert_c_kernel<<<8192, 256, 0, stream>>>(c_ptr, cb);
        ce_main_f16_kernel<<<NBQ, 256, 0, stream>>>(s_ptr, cb, pad_ptr, val_ptr,
                                                    ind_ptr, partials);
    } else {
        ce_main_fp32_kernel<<<NBQ, 256, 0, stream>>>(s_ptr, c_ptr, pad_ptr, val_ptr,
                                                     ind_ptr, partials);
    }
    reduce_kernel<<<64, 256, 0, stream>>>(partials, blk);
    finalize_kernel<<<1, 64, 0, stream>>>(blk, out_ptr);
}

// Round 12
// 119.327 us; speedup vs baseline: 1.3041x; 1.3041x over previous
//
#include <hip/hip_runtime.h>
#include <math.h>

#define B 16
#define N 32
#define M 64
#define D 512
#define NM (N * M)          // 2048
#define NBQ (B * NM)        // 32768
#define NUM_NEGS 32
#define SMOOTHING 0.1f
#define TD0 (1.0f - SMOOTHING)                    // 0.9
#define TDN (SMOOTHING / (float)(NUM_NEGS - 1))   // 0.1/31
#define TDSUM (TD0 + (float)NUM_NEGS * TDN)

typedef __fp16 half2v __attribute__((ext_vector_type(2)));

__device__ __forceinline__ unsigned int pkh(float lo, float hi) {
    half2v h = __builtin_amdgcn_cvt_pkrtz(lo, hi);
    return __builtin_bit_cast(unsigned int, h);
}

__device__ __forceinline__ float fdot2_acc(unsigned int a, unsigned int b, float acc) {
#if __has_builtin(__builtin_amdgcn_fdot2)
    return __builtin_amdgcn_fdot2(__builtin_bit_cast(half2v, a),
                                  __builtin_bit_cast(half2v, b), acc, false);
#else
    half2v ha = __builtin_bit_cast(half2v, a);
    half2v hb = __builtin_bit_cast(half2v, b);
    return acc + (float)ha.x * (float)hb.x + (float)ha.y * (float)hb.y;
#endif
}

__device__ __forceinline__ float dot8h(uint4 a, uint4 b) {
    float acc = fdot2_acc(a.x, b.x, 0.0f);
    acc = fdot2_acc(a.y, b.y, acc);
    acc = fdot2_acc(a.z, b.z, acc);
    acc = fdot2_acc(a.w, b.w, acc);
    return acc;
}

__device__ __forceinline__ uint4 load_s16(const float* __restrict__ s, int row, int lane) {
    const float4* sp = reinterpret_cast<const float4*>(s + (size_t)row * D);
    const float4 a0 = sp[2 * lane];
    const float4 a1 = sp[2 * lane + 1];
    uint4 r;
    r.x = pkh(a0.x, a0.y); r.y = pkh(a0.z, a0.w);
    r.z = pkh(a1.x, a1.y); r.w = pkh(a1.z, a1.w);
    return r;
}

// Streaming c -> f16 (16,777,216 floats, 8 per thread, 8192 x 256 exact).
__global__ __launch_bounds__(256) void convert_c_kernel(
    const float* __restrict__ c, uint4* __restrict__ cb)
{
    const size_t i = (size_t)blockIdx.x * 256 + threadIdx.x;
    const float4* cp = reinterpret_cast<const float4*>(c);
    const float4 a = cp[2 * i];
    const float4 b4 = cp[2 * i + 1];
    uint4 w;
    w.x = pkh(a.x, a.y);   w.y = pkh(a.z, a.w);
    w.z = pkh(b4.x, b4.y); w.w = pkh(b4.z, b4.w);
    cb[i] = w;
}

// ---------- main kernel: round-9 skeleton; valid gather hidden under dots ----------
__global__ __launch_bounds__(256) void ce_main_f16_kernel(
    const float* __restrict__ s,              // (B, NM, D) fp32
    const uint4* __restrict__ cb,             // (B*NM, D/8) f16-packed rows
    const int* __restrict__ pad,
    const int* __restrict__ valid,
    const int* __restrict__ inds,
    float4* __restrict__ partials)
{
    __shared__ float dots[NUM_NEGS + 1];
    __shared__ int   colsh[NUM_NEGS + 1];
    __shared__ int   rowsh[NUM_NEGS + 1];

    // XCD-batch affinity swizzle: XCD x owns batches {x, x+8}.
    const int p  = blockIdx.x;
    const int x  = p & 7;
    const int i  = p >> 3;
    const int b  = x + ((i >> 11) << 3);
    const int q  = i & (NM - 1);
    const int bq = b * NM + q;

    const int tid  = threadIdx.x;
    const int wave = tid >> 6;
    const int lane = tid & 63;

    // Entry: issue address-independent loads (own s-row fp32 + pad).
    const float4* sp = reinterpret_cast<const float4*>(s + (size_t)bq * D);
    const float4 sa0 = sp[2 * lane];
    const float4 sa1 = sp[2 * lane + 1];
    int padraw = 0;
    if (tid == 0) padraw = pad[(size_t)bq * M];

    // Compact setup: 33 threads coalesced-load inds ONLY (no valid here).
    if (tid < NUM_NEGS + 1) {
        int col, row;
        if (tid == 0) {
            col = bq; row = bq;
        } else {
            size_t si = ((size_t)bq * NUM_NEGS + (tid - 1)) * 3;
            int bb = inds[si + 0];
            int rr = inds[si + 1];
            int cc = inds[si + 2];
            col = bb * NM + cc;
            row = bb * NM + rr;
        }
        colsh[tid] = col;
        rowsh[tid] = row;
    }
    __syncthreads();

    // Post-barrier: wave 0 ISSUES the 32 random valid loads now; consumed only
    // in the epilogue, so their ~HBM latency hides under the whole dot phase.
    // valid flat idx = (bb*NM+rr)*NM + cc = row*NM + (col & (NM-1)).
    int vbit = 1;
    if (wave == 0 && lane >= 1 && lane <= NUM_NEGS) {
        vbit = valid[(size_t)rowsh[lane] * NM + (colsh[lane] & (NM - 1))];
    }

    // Own s-row fragment -> f16 registers (global loads already in flight).
    uint4 sh;
    sh.x = pkh(sa0.x, sa0.y); sh.y = pkh(sa0.z, sa0.w);
    sh.z = pkh(sa1.x, sa1.y); sh.w = pkh(sa1.z, sa1.w);

    // 2 groups of 4 concurrent dots: wave w handles {w, w+4, ..., w+28}.
    #pragma unroll
    for (int g = 0; g < 2; ++g) {
        const int j0 = wave + g * 16;
        const int j1 = j0 + 4, j2 = j0 + 8, j3 = j0 + 12;
        const uint4 w0 = cb[(size_t)colsh[j0] * (D / 8) + lane];
        const uint4 w1 = cb[(size_t)colsh[j1] * (D / 8) + lane];
        const uint4 w2 = cb[(size_t)colsh[j2] * (D / 8) + lane];
        const uint4 w3 = cb[(size_t)colsh[j3] * (D / 8) + lane];
        uint4 t0 = sh, t1 = sh, t2 = sh, t3 = sh;
        if (rowsh[j0] != bq) t0 = load_s16(s, rowsh[j0], lane);  // wave-uniform,
        if (rowsh[j1] != bq) t1 = load_s16(s, rowsh[j1], lane);  // never taken for
        if (rowsh[j2] != bq) t2 = load_s16(s, rowsh[j2], lane);  // these inputs
        if (rowsh[j3] != bq) t3 = load_s16(s, rowsh[j3], lane);
        float u0 = dot8h(w0, t0);
        float u1 = dot8h(w1, t1);
        float u2 = dot8h(w2, t2);
        float u3 = dot8h(w3, t3);
        #pragma unroll
        for (int off = 32; off; off >>= 1) {
            u0 += __shfl_xor(u0, off, 64);
            u1 += __shfl_xor(u1, off, 64);
            u2 += __shfl_xor(u2, off, 64);
            u3 += __shfl_xor(u3, off, 64);
        }
        if (lane == 0) {
            dots[j0] = u0;
            dots[j1] = u1;
            dots[j2] = u2;
            dots[j3] = u3;
        }
    }
    if (wave == 0) {   // dot 32
        const uint4 w0 = cb[(size_t)colsh[32] * (D / 8) + lane];
        uint4 t0 = sh;
        if (rowsh[32] != bq) t0 = load_s16(s, rowsh[32], lane);
        float u = dot8h(w0, t0);
        #pragma unroll
        for (int off = 32; off; off >>= 1) u += __shfl_xor(u, off, 64);
        if (lane == 0) dots[32] = u;
    }
    __syncthreads();

    // Wave-parallel epilogue on wave 0 (vbit register arrives here).
    if (wave == 0) {
        float dj = (lane <= NUM_NEGS) ? dots[lane] : -INFINITY;
        if (lane >= 1 && lane <= NUM_NEGS && !vbit) dj = 0.0f;
        float mx = dj;
        #pragma unroll
        for (int off = 32; off; off >>= 1) mx = fmaxf(mx, __shfl_xor(mx, off, 64));
        float e  = (lane <= NUM_NEGS) ? expf(dj - mx) : 0.0f;
        float sn = (lane >= 1 && lane <= NUM_NEGS) ? dj : 0.0f;
        #pragma unroll
        for (int off = 32; off; off >>= 1) {
            e  += __shfl_xor(e, off, 64);
            sn += __shfl_xor(sn, off, 64);
        }
        if (lane == 0) {
            const float num   = dj;             // dots[0]
            const float lse   = mx + logf(e);
            const float chunk = lse * TDSUM - (TD0 * num + TDN * sn);
            const float v     = padraw ? 0.0f : 1.0f;
            const float sim   = 1.0f - fminf(fmaxf(num, -1.0f), 1.0f);
            partials[bq] = make_float4(chunk * v, sim * v, v, 0.0f);
        }
    }
}

// ---------- fallback: fp32 gather, same skeleton (used only if ws too small) ----------
__global__ __launch_bounds__(256) void ce_main_fp32_kernel(
    const float* __restrict__ s, const float* __restrict__ c,
    const int* __restrict__ pad, const int* __restrict__ valid,
    const int* __restrict__ inds, float4* __restrict__ partials)
{
    __shared__ float dots[NUM_NEGS + 1];
    __shared__ int   colsh[NUM_NEGS + 1];
    __shared__ int   rowsh[NUM_NEGS + 1];
    __shared__ unsigned char vmsk[NUM_NEGS + 1];

    const int p  = blockIdx.x;
    const int x  = p & 7;
    const int i  = p >> 3;
    const int b  = x + ((i >> 11) << 3);
    const int q  = i & (NM - 1);
    const int bq = b * NM + q;

    const int tid  = threadIdx.x;
    const int wave = tid >> 6;
    const int lane = tid & 63;

    if (tid < NUM_NEGS + 1) {
        int col, srow, vb;
        if (tid == 0) { col = bq; srow = bq; vb = 1; }
        else {
            size_t si = ((size_t)bq * NUM_NEGS + (tid - 1)) * 3;
            int bb = inds[si + 0]; int rr = inds[si + 1]; int cc = inds[si + 2];
            col = bb * NM + cc; srow = bb * NM + rr;
            vb  = valid[((size_t)bb * NM + rr) * NM + cc] ? 1 : 0;
        }
        colsh[tid] = col; rowsh[tid] = srow; vmsk[tid] = (unsigned char)vb;
    }
    __syncthreads();

    const float4* sp = reinterpret_cast<const float4*>(s + (size_t)bq * D);
    const float4 s0 = sp[lane];
    const float4 s1 = sp[lane + 64];

    for (int j = wave; j < NUM_NEGS + 1; j += 4) {
        const float4* cp = reinterpret_cast<const float4*>(c + (size_t)colsh[j] * D);
        float4 c0 = cp[lane];
        float4 c1 = cp[lane + 64];
        float4 t0 = s0, t1 = s1;
        if (rowsh[j] != bq) {
            const float4* spx = reinterpret_cast<const float4*>(s + (size_t)rowsh[j] * D);
            t0 = spx[lane]; t1 = spx[lane + 64];
        }
        float sum = c0.x * t0.x + c0.y * t0.y + c0.z * t0.z + c0.w * t0.w
                  + c1.x * t1.x + c1.y * t1.y + c1.z * t1.z + c1.w * t1.w;
        #pragma unroll
        for (int off = 32; off; off >>= 1) sum += __shfl_down(sum, off, 64);
        if (lane == 0) dots[j] = vmsk[j] ? sum : 0.0f;
    }
    __syncthreads();

    if (wave == 0) {
        const float dj = (lane <= NUM_NEGS) ? dots[lane] : -INFINITY;
        float mx = dj;
        #pragma unroll
        for (int off = 32; off; off >>= 1) mx = fmaxf(mx, __shfl_xor(mx, off, 64));
        float e  = (lane <= NUM_NEGS) ? expf(dj - mx) : 0.0f;
        float sn = (lane >= 1 && lane <= NUM_NEGS) ? dj : 0.0f;
        #pragma unroll
        for (int off = 32; off; off >>= 1) { e += __shfl_xor(e, off, 64); sn += __shfl_xor(sn, off, 64); }
        if (lane == 0) {
            const float num   = dj;
            const float lse   = mx + logf(e);
            const float chunk = lse * TDSUM - (TD0 * num + TDN * sn);
            const float v     = pad[(size_t)bq * M] ? 0.0f : 1.0f;
            const float sim   = 1.0f - fminf(fmaxf(num, -1.0f), 1.0f);
            partials[bq] = make_float4(chunk * v, sim * v, v, 0.0f);
        }
    }
}

// Stage 2: 64 blocks x 256 threads, grid-stride over NBQ, one partial per block.
__global__ __launch_bounds__(256) void reduce_kernel(
    const float4* __restrict__ partials, float4* __restrict__ blk)
{
    __shared__ float red[3][4];
    float a = 0.0f, bsum = 0.0f, cnt = 0.0f;
    for (int i = blockIdx.x * 256 + threadIdx.x; i < NBQ; i += 64 * 256) {
        float4 pr = partials[i];
        a += pr.x; bsum += pr.y; cnt += pr.z;
    }
    #pragma unroll
    for (int off = 32; off; off >>= 1) {
        a    += __shfl_down(a, off, 64);
        bsum += __shfl_down(bsum, off, 64);
        cnt  += __shfl_down(cnt, off, 64);
    }
    const int wave = threadIdx.x >> 6;
    const int lane = threadIdx.x & 63;
    if (lane == 0) { red[0][wave] = a; red[1][wave] = bsum; red[2][wave] = cnt; }
    __syncthreads();
    if (threadIdx.x == 0) {
        blk[blockIdx.x] = make_float4(red[0][0] + red[0][1] + red[0][2] + red[0][3],
                                      red[1][0] + red[1][1] + red[1][2] + red[1][3],
                                      red[2][0] + red[2][1] + red[2][2] + red[2][3],
                                      0.0f);
    }
}

__global__ void finalize_kernel(const float4* __restrict__ blk,
                                float* __restrict__ out) {
    const int lane = threadIdx.x & 63;
    float4 pr = blk[lane];
    float a = pr.x, bsum = pr.y, cnt = pr.z;
    #pragma unroll
    for (int off = 32; off; off >>= 1) {
        a    += __shfl_down(a, off, 64);
        bsum += __shfl_down(bsum, off, 64);
        cnt  += __shfl_down(cnt, off, 64);
    }
    if (lane == 0) {
        out[0] = a / cnt;     // ce_loss
        out[1] = bsum / cnt;  // sim_loss
    }
}

extern "C" void kernel_launch(void* const* d_in, const int* in_sizes, int n_in,
                              void* d_out, int out_size, void* d_ws, size_t ws_size,
                              hipStream_t stream) {
    const float* s_ptr   = (const float*)d_in[0];
    const float* c_ptr   = (const float*)d_in[1];
    const int*   pad_ptr = (const int*)d_in[2];
    const int*   val_ptr = (const int*)d_in[3];
    const int*   ind_ptr = (const int*)d_in[4];
    float*       out_ptr = (float*)d_out;

    // ws layout: [0, 512K) partials; [512K, +1K) blk; [1M, 1M+32M) c_f16
    float4* partials = (float4*)d_ws;
    float4* blk      = (float4*)((char*)d_ws + (size_t)NBQ * sizeof(float4));
    uint4*  cb       = (uint4*)((char*)d_ws + (1u << 20));
    const size_t need = (1u << 20) + (size_t)B * NM * D * 2;

    if (ws_size >= need) {
        convert_c_kernel<<<8192, 256, 0, stream>>>(c_ptr, cb);
        ce_main_f16_kernel<<<NBQ, 256, 0, stream>>>(s_ptr, cb, pad_ptr, val_ptr,
                                                    ind_ptr, partials);
    } else {
        ce_main_fp32_kernel<<<NBQ, 256, 0, stream>>>(s_ptr, c_ptr, pad_ptr, val_ptr,
                                                     ind_ptr, partials);
    }
    reduce_kernel<<<64, 256, 0, stream>>>(partials, blk);
    finalize_kernel<<<1, 64, 0, stream>>>(blk, out_ptr);
}

// Round 13
// 99.148 us; speedup vs baseline: 1.5695x; 1.2035x over previous
//
#include <hip/hip_runtime.h>
#include <math.h>

#define B 16
#define N 32
#define M 64
#define D 512
#define NM (N * M)          // 2048
#define NBQ (B * NM)        // 32768
#define NUM_NEGS 32
#define SMOOTHING 0.1f
#define TD0 (1.0f - SMOOTHING)                    // 0.9
#define TDN (SMOOTHING / (float)(NUM_NEGS - 1))   // 0.1/31
#define TDSUM (TD0 + (float)NUM_NEGS * TDN)

typedef __fp16 half2v __attribute__((ext_vector_type(2)));

__device__ __forceinline__ unsigned int pkh(float lo, float hi) {
    half2v h = __builtin_amdgcn_cvt_pkrtz(lo, hi);
    return __builtin_bit_cast(unsigned int, h);
}

__device__ __forceinline__ float fdot2_acc(unsigned int a, unsigned int b, float acc) {
#if __has_builtin(__builtin_amdgcn_fdot2)
    return __builtin_amdgcn_fdot2(__builtin_bit_cast(half2v, a),
                                  __builtin_bit_cast(half2v, b), acc, false);
#else
    half2v ha = __builtin_bit_cast(half2v, a);
    half2v hb = __builtin_bit_cast(half2v, b);
    return acc + (float)ha.x * (float)hb.x + (float)ha.y * (float)hb.y;
#endif
}

__device__ __forceinline__ float dot8h(uint4 a, uint4 b) {
    float acc = fdot2_acc(a.x, b.x, 0.0f);
    acc = fdot2_acc(a.y, b.y, acc);
    acc = fdot2_acc(a.z, b.z, acc);
    acc = fdot2_acc(a.w, b.w, acc);
    return acc;
}

__device__ __forceinline__ uint4 load_s16(const float* __restrict__ s, int row, int lane) {
    const float4* sp = reinterpret_cast<const float4*>(s + (size_t)row * D);
    const float4 a0 = sp[2 * lane];
    const float4 a1 = sp[2 * lane + 1];
    uint4 r;
    r.x = pkh(a0.x, a0.y); r.y = pkh(a0.z, a0.w);
    r.z = pkh(a1.x, a1.y); r.w = pkh(a1.z, a1.w);
    return r;
}

// Streaming c -> f16 (16,777,216 floats, 8 per thread, 8192 x 256 exact).
__global__ __launch_bounds__(256) void convert_c_kernel(
    const float* __restrict__ c, uint4* __restrict__ cb)
{
    const size_t i = (size_t)blockIdx.x * 256 + threadIdx.x;
    const float4* cp = reinterpret_cast<const float4*>(c);
    const float4 a = cp[2 * i];
    const float4 b4 = cp[2 * i + 1];
    uint4 w;
    w.x = pkh(a.x, a.y);   w.y = pkh(a.z, a.w);
    w.z = pkh(b4.x, b4.y); w.w = pkh(b4.z, b4.w);
    cb[i] = w;
}

// ---------- main: wave-per-q, zero barriers / zero LDS, fold-reduce ----------
__global__ __launch_bounds__(128) void ce_main_f16_kernel(
    const float* __restrict__ s,              // (B, NM, D) fp32
    const uint4* __restrict__ cb,             // (B*NM, D/8) f16-packed rows
    const int* __restrict__ pad,
    const int* __restrict__ valid,
    const int* __restrict__ inds,
    float4* __restrict__ partials)
{
    // Grid = NBQ/2 blocks of 128 (2 independent waves, one q each).
    // XCD-batch affinity: XCD x owns batches {x, x+8}.
    const int p    = blockIdx.x;
    const int x    = p & 7;
    const int i    = p >> 3;                  // 0..2047
    const int b    = x + ((i >> 10) << 3);    // batch
    const int wave = threadIdx.x >> 6;
    const int lane = threadIdx.x & 63;
    const int q    = (i & 1023) * 2 + wave;
    const int bq   = b * NM + q;

    // Entry: issue address-independent loads (own s-row + pad).
    const float4* sp = reinterpret_cast<const float4*>(s + (size_t)bq * D);
    const float4 sa0 = sp[2 * lane];
    const float4 sa1 = sp[2 * lane + 1];
    const int padraw = pad[(size_t)bq * M];   // wave-uniform broadcast load

    // Per-lane setup: lane k (1..32) owns neg k-th entry (j = k).
    int col_r = bq, row_r = bq;
    int vbit = 1;
    if (lane >= 1 && lane <= NUM_NEGS) {
        const size_t si = ((size_t)bq * NUM_NEGS + (lane - 1)) * 3;
        const int bb = inds[si + 0];
        const int rr = inds[si + 1];
        const int cc = inds[si + 2];
        col_r = bb * NM + cc;
        row_r = bb * NM + rr;
        // Issued here, consumed only in the epilogue (hides under dot phase).
        vbit = valid[(size_t)row_r * NM + (col_r & (NM - 1))];
    }

    // Own s-row -> f16 registers.
    uint4 sh;
    sh.x = pkh(sa0.x, sa0.y); sh.y = pkh(sa0.z, sa0.w);
    sh.z = pkh(sa1.x, sa1.y); sh.w = pkh(sa1.z, sa1.w);

    // j = 32 issued first (deepest in flight).
    const int col32 = __shfl(col_r, 32, 64);
    const int row32 = __shfl(row_r, 32, 64);
    const uint4 w32 = cb[(size_t)col32 * (D / 8) + lane];

    // 4 batches of 8 dots: batch t covers j = t*8 + m, m=0..7 (j=0 is diag).
    float dv0 = 0.f, dv1 = 0.f, dv2 = 0.f, dv3 = 0.f;
    #pragma unroll
    for (int t = 0; t < 4; ++t) {
        uint4 w[8];
        #pragma unroll
        for (int m = 0; m < 8; ++m) {
            const int j = t * 8 + m;
            const int col = __shfl(col_r, j, 64);     // literal lane -> readlane
            w[m] = cb[(size_t)col * (D / 8) + lane];
        }
        float u[8];
        #pragma unroll
        for (int m = 0; m < 8; ++m) {
            const int j = t * 8 + m;
            const int row = __shfl(row_r, j, 64);
            uint4 tt = sh;
            if (row != bq) tt = load_s16(s, row, lane);   // never taken here
            u[m] = dot8h(w[m], tt);
        }
        // Fold-reduce 8 values over 64 lanes (round-10 proven): 3 folds + 3 bfly.
        const int b0 = lane & 1, b1 = lane & 2, b2 = lane & 4;
        float n0 = (b0 ? u[1] : u[0]) + __shfl_xor(b0 ? u[0] : u[1], 1, 64);
        float n1 = (b0 ? u[3] : u[2]) + __shfl_xor(b0 ? u[2] : u[3], 1, 64);
        float n2 = (b0 ? u[5] : u[4]) + __shfl_xor(b0 ? u[4] : u[5], 1, 64);
        float n3 = (b0 ? u[7] : u[6]) + __shfl_xor(b0 ? u[6] : u[7], 1, 64);
        float m0 = (b1 ? n1 : n0) + __shfl_xor(b1 ? n0 : n1, 2, 64);
        float m1 = (b1 ? n3 : n2) + __shfl_xor(b1 ? n2 : n3, 2, 64);
        float w8 = (b2 ? m1 : m0) + __shfl_xor(b2 ? m0 : m1, 4, 64);
        w8 += __shfl_xor(w8, 8, 64);
        w8 += __shfl_xor(w8, 16, 64);
        w8 += __shfl_xor(w8, 32, 64);
        // Lane L holds sum of u[L&7] -> dot j = t*8 + (L&7).
        if (t == 0) dv0 = w8; else if (t == 1) dv1 = w8;
        else if (t == 2) dv2 = w8; else dv3 = w8;
    }

    // Dot 32.
    uint4 t32 = sh;
    if (row32 != bq) t32 = load_s16(s, row32, lane);
    float d32 = dot8h(w32, t32);
    #pragma unroll
    for (int off = 32; off; off >>= 1) d32 += __shfl_xor(d32, off, 64);

    // In-wave epilogue: lane k holds dot k (k<=31 via named select; 32 via d32).
    const int sel = lane >> 3;   // 0..3 for lanes 0..31
    float dj;
    if (lane < 32) {
        dj = (sel == 0) ? dv0 : (sel == 1) ? dv1 : (sel == 2) ? dv2 : dv3;
        if (lane >= 1 && !vbit) dj = 0.0f;    // lane 0 = diag, never masked
    } else if (lane == 32) {
        dj = vbit ? d32 : 0.0f;               // lane 32 owns j=32's vbit
    } else {
        dj = -INFINITY;
    }
    float mx = dj;
    #pragma unroll
    for (int off = 32; off; off >>= 1) mx = fmaxf(mx, __shfl_xor(mx, off, 64));
    float e  = (lane <= NUM_NEGS) ? expf(dj - mx) : 0.0f;
    float sn = (lane >= 1 && lane <= NUM_NEGS) ? dj : 0.0f;
    #pragma unroll
    for (int off = 32; off; off >>= 1) {
        e  += __shfl_xor(e, off, 64);
        sn += __shfl_xor(sn, off, 64);
    }
    if (lane == 0) {
        const float num   = dj;               // diag
        const float lse   = mx + logf(e);
        const float chunk = lse * TDSUM - (TD0 * num + TDN * sn);
        const float v     = padraw ? 0.0f : 1.0f;
        const float sim   = 1.0f - fminf(fmaxf(num, -1.0f), 1.0f);
        partials[bq] = make_float4(chunk * v, sim * v, v, 0.0f);
    }
}

// ---------- fallback: round-12 fp32 kernel (used only if ws too small) ----------
__global__ __launch_bounds__(256) void ce_main_fp32_kernel(
    const float* __restrict__ s, const float* __restrict__ c,
    const int* __restrict__ pad, const int* __restrict__ valid,
    const int* __restrict__ inds, float4* __restrict__ partials)
{
    __shared__ float dots[NUM_NEGS + 1];
    __shared__ int   colsh[NUM_NEGS + 1];
    __shared__ int   rowsh[NUM_NEGS + 1];
    __shared__ unsigned char vmsk[NUM_NEGS + 1];

    const int p  = blockIdx.x;
    const int x  = p & 7;
    const int i  = p >> 3;
    const int b  = x + ((i >> 11) << 3);
    const int q  = i & (NM - 1);
    const int bq = b * NM + q;

    const int tid  = threadIdx.x;
    const int wave = tid >> 6;
    const int lane = tid & 63;

    if (tid < NUM_NEGS + 1) {
        int col, srow, vb;
        if (tid == 0) { col = bq; srow = bq; vb = 1; }
        else {
            size_t si = ((size_t)bq * NUM_NEGS + (tid - 1)) * 3;
            int bb = inds[si + 0]; int rr = inds[si + 1]; int cc = inds[si + 2];
            col = bb * NM + cc; srow = bb * NM + rr;
            vb  = valid[((size_t)bb * NM + rr) * NM + cc] ? 1 : 0;
        }
        colsh[tid] = col; rowsh[tid] = srow; vmsk[tid] = (unsigned char)vb;
    }
    __syncthreads();

    const float4* sp = reinterpret_cast<const float4*>(s + (size_t)bq * D);
    const float4 s0 = sp[lane];
    const float4 s1 = sp[lane + 64];

    for (int j = wave; j < NUM_NEGS + 1; j += 4) {
        const float4* cp = reinterpret_cast<const float4*>(c + (size_t)colsh[j] * D);
        float4 c0 = cp[lane];
        float4 c1 = cp[lane + 64];
        float4 t0 = s0, t1 = s1;
        if (rowsh[j] != bq) {
            const float4* spx = reinterpret_cast<const float4*>(s + (size_t)rowsh[j] * D);
            t0 = spx[lane]; t1 = spx[lane + 64];
        }
        float sum = c0.x * t0.x + c0.y * t0.y + c0.z * t0.z + c0.w * t0.w
                  + c1.x * t1.x + c1.y * t1.y + c1.z * t1.z + c1.w * t1.w;
        #pragma unroll
        for (int off = 32; off; off >>= 1) sum += __shfl_down(sum, off, 64);
        if (lane == 0) dots[j] = vmsk[j] ? sum : 0.0f;
    }
    __syncthreads();

    if (wave == 0) {
        const float dj = (lane <= NUM_NEGS) ? dots[lane] : -INFINITY;
        float mx = dj;
        #pragma unroll
        for (int off = 32; off; off >>= 1) mx = fmaxf(mx, __shfl_xor(mx, off, 64));
        float e  = (lane <= NUM_NEGS) ? expf(dj - mx) : 0.0f;
        float sn = (lane >= 1 && lane <= NUM_NEGS) ? dj : 0.0f;
        #pragma unroll
        for (int off = 32; off; off >>= 1) { e += __shfl_xor(e, off, 64); sn += __shfl_xor(sn, off, 64); }
        if (lane == 0) {
            const float num   = dj;
            const float lse   = mx + logf(e);
            const float chunk = lse * TDSUM - (TD0 * num + TDN * sn);
            const float v     = pad[(size_t)bq * M] ? 0.0f : 1.0f;
            const float sim   = 1.0f - fminf(fmaxf(num, -1.0f), 1.0f);
            partials[bq] = make_float4(chunk * v, sim * v, v, 0.0f);
        }
    }
}

// Stage 2: 64 blocks x 256 threads, grid-stride over NBQ, one partial per block.
__global__ __launch_bounds__(256) void reduce_kernel(
    const float4* __restrict__ partials, float4* __restrict__ blk)
{
    __shared__ float red[3][4];
    float a = 0.0f, bsum = 0.0f, cnt = 0.0f;
    for (int i = blockIdx.x * 256 + threadIdx.x; i < NBQ; i += 64 * 256) {
        float4 pr = partials[i];
        a += pr.x; bsum += pr.y; cnt += pr.z;
    }
    #pragma unroll
    for (int off = 32; off; off >>= 1) {
        a    += __shfl_down(a, off, 64);
        bsum += __shfl_down(bsum, off, 64);
        cnt  += __shfl_down(cnt, off, 64);
    }
    const int wave = threadIdx.x >> 6;
    const int lane = threadIdx.x & 63;
    if (lane == 0) { red[0][wave] = a; red[1][wave] = bsum; red[2][wave] = cnt; }
    __syncthreads();
    if (threadIdx.x == 0) {
        blk[blockIdx.x] = make_float4(red[0][0] + red[0][1] + red[0][2] + red[0][3],
                                      red[1][0] + red[1][1] + red[1][2] + red[1][3],
                                      red[2][0] + red[2][1] + red[2][2] + red[2][3],
                                      0.0f);
    }
}

__global__ void finalize_kernel(const float4* __restrict__ blk,
                                float* __restrict__ out) {
    const int lane = threadIdx.x & 63;
    float4 pr = blk[lane];
    float a = pr.x, bsum = pr.y, cnt = pr.z;
    #pragma unroll
    for (int off = 32; off; off >>= 1) {
        a    += __shfl_down(a, off, 64);
        bsum += __shfl_down(bsum, off, 64);
        cnt  += __shfl_down(cnt, off, 64);
    }
    if (lane == 0) {
        out[0] = a / cnt;     // ce_loss
        out[1] = bsum / cnt;  // sim_loss
    }
}

extern "C" void kernel_launch(void* const* d_in, const int* in_sizes, int n_in,
                              void* d_out, int out_size, void* d_ws, size_t ws_size,
                              hipStream_t stream) {
    const float* s_ptr   = (const float*)d_in[0];
    const float* c_ptr   = (const float*)d_in[1];
    const int*   pad_ptr = (const int*)d_in[2];
    const int*   val_ptr = (const int*)d_in[3];
    const int*   ind_ptr = (const int*)d_in[4];
    float*       out_ptr = (float*)d_out;

    // ws layout: [0, 512K) partials; [512K, +1K) blk; [1M, 1M+32M) c_f16
    float4* partials = (float4*)d_ws;
    float4* blk      = (float4*)((char*)d_ws + (size_t)NBQ * sizeof(float4));
    uint4*  cb       = (uint4*)((char*)d_ws + (1u << 20));
    const size_t need = (1u << 20) + (size_t)B * NM * D * 2;

    if (ws_size >= need) {
        convert_c_kernel<<<8192, 256, 0, stream>>>(c_ptr, cb);
        ce_main_f16_kernel<<<NBQ / 2, 128, 0, stream>>>(s_ptr, cb, pad_ptr,
                                                        val_ptr, ind_ptr, partials);
    } else {
        ce_main_fp32_kernel<<<NBQ, 256, 0, stream>>>(s_ptr, c_ptr, pad_ptr, val_ptr,
                                                     ind_ptr, partials);
    }
    reduce_kernel<<<64, 256, 0, stream>>>(partials, blk);
    finalize_kernel<<<1, 64, 0, stream>>>(blk, out_ptr);
}

// Round 14
// 98.289 us; speedup vs baseline: 1.5832x; 1.0087x over previous
//
#include <hip/hip_runtime.h>
#include <math.h>

#define B 16
#define N 32
#define M 64
#define D 512
#define NM (N * M)          // 2048
#define NBQ (B * NM)        // 32768
#define NUM_NEGS 32
#define SMOOTHING 0.1f
#define TD0 (1.0f - SMOOTHING)                    // 0.9
#define TDN (SMOOTHING / (float)(NUM_NEGS - 1))   // 0.1/31
#define TDSUM (TD0 + (float)NUM_NEGS * TDN)

typedef __fp16 half2v __attribute__((ext_vector_type(2)));

__device__ __forceinline__ unsigned int pkh(float lo, float hi) {
    half2v h = __builtin_amdgcn_cvt_pkrtz(lo, hi);
    return __builtin_bit_cast(unsigned int, h);
}

__device__ __forceinline__ float fdot2_acc(unsigned int a, unsigned int b, float acc) {
#if __has_builtin(__builtin_amdgcn_fdot2)
    return __builtin_amdgcn_fdot2(__builtin_bit_cast(half2v, a),
                                  __builtin_bit_cast(half2v, b), acc, false);
#else
    half2v ha = __builtin_bit_cast(half2v, a);
    half2v hb = __builtin_bit_cast(half2v, b);
    return acc + (float)ha.x * (float)hb.x + (float)ha.y * (float)hb.y;
#endif
}

__device__ __forceinline__ float dot8h(uint4 a, uint4 b) {
    float acc = fdot2_acc(a.x, b.x, 0.0f);
    acc = fdot2_acc(a.y, b.y, acc);
    acc = fdot2_acc(a.z, b.z, acc);
    acc = fdot2_acc(a.w, b.w, acc);
    return acc;
}

__device__ __forceinline__ uint4 load_s16(const float* __restrict__ s, int row, int lane) {
    const float4* sp = reinterpret_cast<const float4*>(s + (size_t)row * D);
    const float4 a0 = sp[2 * lane];
    const float4 a1 = sp[2 * lane + 1];
    uint4 r;
    r.x = pkh(a0.x, a0.y); r.y = pkh(a0.z, a0.w);
    r.z = pkh(a1.x, a1.y); r.w = pkh(a1.z, a1.w);
    return r;
}

// Streaming c -> f16 (16,777,216 floats, 8 per thread, 8192 x 256 exact).
__global__ __launch_bounds__(256) void convert_c_kernel(
    const float* __restrict__ c, uint4* __restrict__ cb)
{
    const size_t i = (size_t)blockIdx.x * 256 + threadIdx.x;
    const float4* cp = reinterpret_cast<const float4*>(c);
    const float4 a = cp[2 * i];
    const float4 b4 = cp[2 * i + 1];
    uint4 w;
    w.x = pkh(a.x, a.y);   w.y = pkh(a.z, a.w);
    w.z = pkh(b4.x, b4.y); w.w = pkh(b4.z, b4.w);
    cb[i] = w;
}

// ---------- main: wave-per-q, zero barriers / zero LDS, fold-reduce ----------
__global__ __launch_bounds__(128) void ce_main_f16_kernel(
    const float* __restrict__ s,              // (B, NM, D) fp32
    const uint4* __restrict__ cb,             // (B*NM, D/8) f16-packed rows
    const int* __restrict__ pad,
    const int* __restrict__ valid,
    const int* __restrict__ inds,
    float4* __restrict__ partials)
{
    // Grid = NBQ/2 blocks of 128 (2 independent waves, one q each).
    // XCD-batch affinity: XCD x owns batches {x, x+8}.
    const int p    = blockIdx.x;
    const int x    = p & 7;
    const int i    = p >> 3;                  // 0..2047
    const int b    = x + ((i >> 10) << 3);    // batch
    const int wave = threadIdx.x >> 6;
    const int lane = threadIdx.x & 63;
    const int q    = (i & 1023) * 2 + wave;
    const int bq   = b * NM + q;

    // Entry: issue address-independent loads (own s-row + pad).
    const float4* sp = reinterpret_cast<const float4*>(s + (size_t)bq * D);
    const float4 sa0 = sp[2 * lane];
    const float4 sa1 = sp[2 * lane + 1];
    const int padraw = pad[(size_t)bq * M];   // wave-uniform broadcast load

    // Per-lane setup: lane k (1..32) owns neg entry j = k.
    int col_r = bq, row_r = bq;
    int vbit = 1;
    if (lane >= 1 && lane <= NUM_NEGS) {
        const size_t si = ((size_t)bq * NUM_NEGS + (lane - 1)) * 3;
        const int bb = inds[si + 0];
        const int rr = inds[si + 1];
        const int cc = inds[si + 2];
        col_r = bb * NM + cc;
        row_r = bb * NM + rr;
        // Issued here, consumed only in the epilogue (hides under dot phase).
        vbit = valid[(size_t)row_r * NM + (col_r & (NM - 1))];
    }

    // One ballot replaces 33 per-dot row broadcasts: bit j set iff row_j == bq
    // (lanes > 32 hold bq, so their bits are 1). Wave-uniform scalar mask.
    const unsigned long long rowmatch = __ballot(row_r == bq);

    // Own s-row -> f16 registers.
    uint4 sh;
    sh.x = pkh(sa0.x, sa0.y); sh.y = pkh(sa0.z, sa0.w);
    sh.z = pkh(sa1.x, sa1.y); sh.w = pkh(sa1.z, sa1.w);

    // j = 32 issued first (deepest in flight).
    const int col32 = __shfl(col_r, 32, 64);
    const uint4 w32 = cb[(size_t)col32 * (D / 8) + lane];

    // 4 batches of 8 dots: batch t covers j = t*8 + m, m=0..7 (j=0 is diag).
    float dv0 = 0.f, dv1 = 0.f, dv2 = 0.f, dv3 = 0.f;
    #pragma unroll
    for (int t = 0; t < 4; ++t) {
        uint4 w[8];
        #pragma unroll
        for (int m = 0; m < 8; ++m) {
            const int j = t * 8 + m;
            const int col = __shfl(col_r, j, 64);     // literal lane -> readlane
            w[m] = cb[(size_t)col * (D / 8) + lane];
        }
        float u[8];
        #pragma unroll
        for (int m = 0; m < 8; ++m) {
            const int j = t * 8 + m;
            uint4 tt = sh;
            if (!((rowmatch >> j) & 1ULL)) {          // scalar test; never taken
                const int row = __shfl(row_r, j, 64);
                tt = load_s16(s, row, lane);
            }
            u[m] = dot8h(w[m], tt);
        }
        // Fold-reduce 8 values over 64 lanes: 3 folds + 3 butterflies.
        const int b0 = lane & 1, b1 = lane & 2, b2 = lane & 4;
        float n0 = (b0 ? u[1] : u[0]) + __shfl_xor(b0 ? u[0] : u[1], 1, 64);
        float n1 = (b0 ? u[3] : u[2]) + __shfl_xor(b0 ? u[2] : u[3], 1, 64);
        float n2 = (b0 ? u[5] : u[4]) + __shfl_xor(b0 ? u[4] : u[5], 1, 64);
        float n3 = (b0 ? u[7] : u[6]) + __shfl_xor(b0 ? u[6] : u[7], 1, 64);
        float m0 = (b1 ? n1 : n0) + __shfl_xor(b1 ? n0 : n1, 2, 64);
        float m1 = (b1 ? n3 : n2) + __shfl_xor(b1 ? n2 : n3, 2, 64);
        float w8 = (b2 ? m1 : m0) + __shfl_xor(b2 ? m0 : m1, 4, 64);
        w8 += __shfl_xor(w8, 8, 64);
        w8 += __shfl_xor(w8, 16, 64);
        w8 += __shfl_xor(w8, 32, 64);
        // Lane L holds sum of u[L&7] -> dot j = t*8 + (L&7).
        if (t == 0) dv0 = w8; else if (t == 1) dv1 = w8;
        else if (t == 2) dv2 = w8; else dv3 = w8;
    }

    // Dot 32.
    uint4 t32 = sh;
    if (!((rowmatch >> 32) & 1ULL)) {
        const int row32 = __shfl(row_r, 32, 64);
        t32 = load_s16(s, row32, lane);
    }
    float d32 = dot8h(w32, t32);
    #pragma unroll
    for (int off = 32; off; off >>= 1) d32 += __shfl_xor(d32, off, 64);

    // In-wave epilogue: lane k holds dot k (k<=31 via named select; 32 via d32).
    const int sel = lane >> 3;   // 0..3 for lanes 0..31
    float dj;
    if (lane < 32) {
        dj = (sel == 0) ? dv0 : (sel == 1) ? dv1 : (sel == 2) ? dv2 : dv3;
        if (lane >= 1 && !vbit) dj = 0.0f;    // lane 0 = diag, never masked
    } else if (lane == 32) {
        dj = vbit ? d32 : 0.0f;               // lane 32 owns j=32's vbit
    } else {
        dj = -INFINITY;
    }
    float mx = dj;
    #pragma unroll
    for (int off = 32; off; off >>= 1) mx = fmaxf(mx, __shfl_xor(mx, off, 64));
    float e  = (lane <= NUM_NEGS) ? expf(dj - mx) : 0.0f;
    float sn = (lane >= 1 && lane <= NUM_NEGS) ? dj : 0.0f;
    #pragma unroll
    for (int off = 32; off; off >>= 1) {
        e  += __shfl_xor(e, off, 64);
        sn += __shfl_xor(sn, off, 64);
    }
    if (lane == 0) {
        const float num   = dj;               // diag
        const float lse   = mx + logf(e);
        const float chunk = lse * TDSUM - (TD0 * num + TDN * sn);
        const float v     = padraw ? 0.0f : 1.0f;
        const float sim   = 1.0f - fminf(fmaxf(num, -1.0f), 1.0f);
        partials[bq] = make_float4(chunk * v, sim * v, v, 0.0f);
    }
}

// ---------- fallback: fp32 gather (used only if ws too small) ----------
__global__ __launch_bounds__(256) void ce_main_fp32_kernel(
    const float* __restrict__ s, const float* __restrict__ c,
    const int* __restrict__ pad, const int* __restrict__ valid,
    const int* __restrict__ inds, float4* __restrict__ partials)
{
    __shared__ float dots[NUM_NEGS + 1];
    __shared__ int   colsh[NUM_NEGS + 1];
    __shared__ int   rowsh[NUM_NEGS + 1];
    __shared__ unsigned char vmsk[NUM_NEGS + 1];

    const int p  = blockIdx.x;
    const int x  = p & 7;
    const int i  = p >> 3;
    const int b  = x + ((i >> 11) << 3);
    const int q  = i & (NM - 1);
    const int bq = b * NM + q;

    const int tid  = threadIdx.x;
    const int wave = tid >> 6;
    const int lane = tid & 63;

    if (tid < NUM_NEGS + 1) {
        int col, srow, vb;
        if (tid == 0) { col = bq; srow = bq; vb = 1; }
        else {
            size_t si = ((size_t)bq * NUM_NEGS + (tid - 1)) * 3;
            int bb = inds[si + 0]; int rr = inds[si + 1]; int cc = inds[si + 2];
            col = bb * NM + cc; srow = bb * NM + rr;
            vb  = valid[((size_t)bb * NM + rr) * NM + cc] ? 1 : 0;
        }
        colsh[tid] = col; rowsh[tid] = srow; vmsk[tid] = (unsigned char)vb;
    }
    __syncthreads();

    const float4* sp = reinterpret_cast<const float4*>(s + (size_t)bq * D);
    const float4 s0 = sp[lane];
    const float4 s1 = sp[lane + 64];

    for (int j = wave; j < NUM_NEGS + 1; j += 4) {
        const float4* cp = reinterpret_cast<const float4*>(c + (size_t)colsh[j] * D);
        float4 c0 = cp[lane];
        float4 c1 = cp[lane + 64];
        float4 t0 = s0, t1 = s1;
        if (rowsh[j] != bq) {
            const float4* spx = reinterpret_cast<const float4*>(s + (size_t)rowsh[j] * D);
            t0 = spx[lane]; t1 = spx[lane + 64];
        }
        float sum = c0.x * t0.x + c0.y * t0.y + c0.z * t0.z + c0.w * t0.w
                  + c1.x * t1.x + c1.y * t1.y + c1.z * t1.z + c1.w * t1.w;
        #pragma unroll
        for (int off = 32; off; off >>= 1) sum += __shfl_down(sum, off, 64);
        if (lane == 0) dots[j] = vmsk[j] ? sum : 0.0f;
    }
    __syncthreads();

    if (wave == 0) {
        const float dj = (lane <= NUM_NEGS) ? dots[lane] : -INFINITY;
        float mx = dj;
        #pragma unroll
        for (int off = 32; off; off >>= 1) mx = fmaxf(mx, __shfl_xor(mx, off, 64));
        float e  = (lane <= NUM_NEGS) ? expf(dj - mx) : 0.0f;
        float sn = (lane >= 1 && lane <= NUM_NEGS) ? dj : 0.0f;
        #pragma unroll
        for (int off = 32; off; off >>= 1) { e += __shfl_xor(e, off, 64); sn += __shfl_xor(sn, off, 64); }
        if (lane == 0) {
            const float num   = dj;
            const float lse   = mx + logf(e);
            const float chunk = lse * TDSUM - (TD0 * num + TDN * sn);
            const float v     = pad[(size_t)bq * M] ? 0.0f : 1.0f;
            const float sim   = 1.0f - fminf(fmaxf(num, -1.0f), 1.0f);
            partials[bq] = make_float4(chunk * v, sim * v, v, 0.0f);
        }
    }
}

// Stage 2: 64 blocks x 256 threads, grid-stride over NBQ, one partial per block.
__global__ __launch_bounds__(256) void reduce_kernel(
    const float4* __restrict__ partials, float4* __restrict__ blk)
{
    __shared__ float red[3][4];
    float a = 0.0f, bsum = 0.0f, cnt = 0.0f;
    for (int i = blockIdx.x * 256 + threadIdx.x; i < NBQ; i += 64 * 256) {
        float4 pr = partials[i];
        a += pr.x; bsum += pr.y; cnt += pr.z;
    }
    #pragma unroll
    for (int off = 32; off; off >>= 1) {
        a    += __shfl_down(a, off, 64);
        bsum += __shfl_down(bsum, off, 64);
        cnt  += __shfl_down(cnt, off, 64);
    }
    const int wave = threadIdx.x >> 6;
    const int lane = threadIdx.x & 63;
    if (lane == 0) { red[0][wave] = a; red[1][wave] = bsum; red[2][wave] = cnt; }
    __syncthreads();
    if (threadIdx.x == 0) {
        blk[blockIdx.x] = make_float4(red[0][0] + red[0][1] + red[0][2] + red[0][3],
                                      red[1][0] + red[1][1] + red[1][2] + red[1][3],
                                      red[2][0] + red[2][1] + red[2][2] + red[2][3],
                                      0.0f);
    }
}

__global__ void finalize_kernel(const float4* __restrict__ blk,
                                float* __restrict__ out) {
    const int lane = threadIdx.x & 63;
    float4 pr = blk[lane];
    float a = pr.x, bsum = pr.y, cnt = pr.z;
    #pragma unroll
    for (int off = 32; off; off >>= 1) {
        a    += __shfl_down(a, off, 64);
        bsum += __shfl_down(bsum, off, 64);
        cnt  += __shfl_down(cnt, off, 64);
    }
    if (lane == 0) {
        out[0] = a / cnt;     // ce_loss
        out[1] = bsum / cnt;  // sim_loss
    }
}

extern "C" void kernel_launch(void* const* d_in, const int* in_sizes, int n_in,
                              void* d_out, int out_size, void* d_ws, size_t ws_size,
                              hipStream_t stream) {
    const float* s_ptr   = (const float*)d_in[0];
    const float* c_ptr   = (const float*)d_in[1];
    const int*   pad_ptr = (const int*)d_in[2];
    const int*   val_ptr = (const int*)d_in[3];
    const int*   ind_ptr = (const int*)d_in[4];
    float*       out_ptr = (float*)d_out;

    // ws layout: [0, 512K) partials; [512K, +1K) blk; [1M, 1M+32M) c_f16
    float4* partials = (float4*)d_ws;
    float4* blk      = (float4*)((char*)d_ws + (size_t)NBQ * sizeof(float4));
    uint4*  cb       = (uint4*)((char*)d_ws + (1u << 20));
    const size_t need = (1u << 20) + (size_t)B * NM * D * 2;

    if (ws_size >= need) {
        convert_c_kernel<<<8192, 256, 0, stream>>>(c_ptr, cb);
        ce_main_f16_kernel<<<NBQ / 2, 128, 0, stream>>>(s_ptr, cb, pad_ptr,
                                                        val_ptr, ind_ptr, partials);
    } else {
        ce_main_fp32_kernel<<<NBQ, 256, 0, stream>>>(s_ptr, c_ptr, pad_ptr, val_ptr,
                                                     ind_ptr, partials);
    }
    reduce_kernel<<<64, 256, 0, stream>>>(partials, blk);
    finalize_kernel<<<1, 64, 0, stream>>>(blk, out_ptr);
}